// Round 6
// baseline (55.725 us; speedup 1.0000x reference)
//
#include <hip/hip_runtime.h>
#include <math.h>

typedef __attribute__((ext_vector_type(8))) _Float16 half8;
typedef __attribute__((ext_vector_type(4))) float f32x4;
typedef __attribute__((ext_vector_type(2))) float f32x2;

constexpr int B_   = 32768;
constexpr int NKPS = 14;
constexpr int DIM  = 42;
constexpr int H1_  = 1024;
constexpr int NDOF = 7;

// ---------------------------------------------------------------------------
// K0: pack B = [W1_hi(42); W1_hi(42); W1_lo(42); b1_hi; b1_lo] (K=128 x N=1024,
// f16) in per-lane MFMA fragment order:
//   B1f[((ks*64+nt)*64+lane)*8+j] = B[k=ks*32+(lane>>4)*8+j][n=nt*16+(lane&15)]
// Pairing with A = [x_hi | x_lo | x_hi | 1 | 1] gives
//   x_hi*W_hi + x_lo*W_hi + x_hi*W_lo + b1_hi + b1_lo  (err ~ x_lo*W_lo ~ 2^-22)
// Also pads W2 [1024][7] -> W2p [1024][8] f32.
// ---------------------------------------------------------------------------
__global__ __launch_bounds__(256)
void prep_kernel(const float* __restrict__ W1, const float* __restrict__ b1,
                 const float* __restrict__ W2,
                 _Float16* __restrict__ B1f, float* __restrict__ W2p)
{
    const int T = blockIdx.x * 256 + threadIdx.x;
    if (T < 16384) {
        const int lane  = T & 63;
        const int ntile = (T >> 6) & 63;
        const int ks    = T >> 12;               // 0..3
        const int n     = ntile * 16 + (lane & 15);
        const int kbase = ks * 32 + ((lane >> 4) << 3);
        half8 s;
#pragma unroll
        for (int j = 0; j < 8; ++j) {
            const int k = kbase + j;
            _Float16 hv;
            if (k < 42) {
                hv = (_Float16)W1[k * H1_ + n];
            } else if (k < 84) {
                hv = (_Float16)W1[(k - 42) * H1_ + n];
            } else if (k < 126) {
                const float x = W1[(k - 84) * H1_ + n];
                const _Float16 hi = (_Float16)x;
                hv = (_Float16)(x - (float)hi);
            } else if (k == 126) {
                hv = (_Float16)b1[n];
            } else {
                const float x = b1[n];
                const _Float16 hi = (_Float16)x;
                hv = (_Float16)(x - (float)hi);
            }
            s[j] = hv;
        }
        *((half8*)(B1f + (long)T * 8)) = s;
    } else if (T < 16384 + 1024) {
        const int n = T - 16384;
#pragma unroll
        for (int d = 0; d < 7; ++d) W2p[n * 8 + d] = W2[n * 7 + d];
        W2p[n * 8 + 7] = 0.f;
    }
}

#define JROT(app, aqq, apq, arp, arq, v0p, v0q, v1p, v1q, v2p, v2q) do { \
    double _apq = (apq); \
    if (fabs(_apq) > 1e-300) { \
        double _tau = ((aqq) - (app)) / (2.0 * _apq); \
        double _t = ((_tau >= 0.0) ? 1.0 : -1.0) / (fabs(_tau) + sqrt(1.0 + _tau*_tau)); \
        double _c = 1.0 / sqrt(1.0 + _t*_t); \
        double _s = _t * _c; \
        (app) -= _t * _apq; \
        (aqq) += _t * _apq; \
        (apq) = 0.0; \
        { double _rp = (arp), _rq = (arq); \
          (arp) = _c*_rp - _s*_rq; (arq) = _s*_rp + _c*_rq; } \
        { double _v = (v0p); (v0p) = _c*_v - _s*(v0q); (v0q) = _s*_v + _c*(v0q); } \
        { double _v = (v1p); (v1p) = _c*_v - _s*(v1q); (v1q) = _s*_v + _c*(v1q); } \
        { double _v = (v2p); (v2p) = _c*_v - _s*(v2q); (v2q) = _s*_v + _c*(v2q); } \
    } \
} while (0)

#define SWAP_EIG(ea, eb, va0, vb0, va1, vb1, va2, vb2) do { \
    double _tm; \
    _tm = (ea); (ea) = (eb); (eb) = _tm; \
    _tm = (va0); (va0) = (vb0); (vb0) = _tm; \
    _tm = (va1); (va1) = (vb1); (vb1) = _tm; \
    _tm = (va2); (va2) = (vb2); (vb2) = _tm; \
} while (0)

// ---------------------------------------------------------------------------
// K1 (fused): MLP via f16 MFMA (K=128, 3-term split), swapped operands ->
// C[n][m] so the hidden reduction is within-lane. 256 thr / 4 waves per
// block, M-tile 32 (mt=2), wave w covers ntiles w*16..w*16+15.
// After the angle reduce, threads 0..31 run FK + Kabsch for the tile's rows.
// ---------------------------------------------------------------------------
__global__ __launch_bounds__(256, 4)
void mlp_fk_kernel(const float* __restrict__ joints,
                   const _Float16* __restrict__ B1f,
                   const float* __restrict__ W2p,
                   const float* __restrict__ b2,
                   float* __restrict__ out)
{
    __shared__ _Float16 Alds[32][136];         // 32 rows x K=128 (+8 pad)
    __shared__ float sbuf[32][8];              // angle accumulators

    const int  tid  = threadIdx.x;
    const long bm   = (long)blockIdx.x * 32;
    const int  lane = tid & 63;
    const int  w    = tid >> 6;     // wave 0..3
    const int  g    = lane >> 4;    // 0..3
    const int  lm   = lane & 15;

    ((float*)sbuf)[tid] = 0.f;

    // ---- stage A: x split [x_hi | x_lo | x_hi | 1 | 1] as f16 ----
    {
        const int r  = tid >> 3;      // 0..31
        const int c8 = tid & 7;
        const float* jr = joints + (bm + r) * DIM;
#pragma unroll
        for (int h2 = 0; h2 < 2; ++h2) {
            const int gi = c8 + h2 * 8;   // 0..15
            half8 s;
#pragma unroll
            for (int j = 0; j < 8; ++j) {
                const int k = gi * 8 + j;
                _Float16 hv;
                if (k < 42) {
                    hv = (_Float16)(jr[k] - jr[k % 3]);
                } else if (k < 84) {
                    const int km = k - 42;
                    const float x = jr[km] - jr[km % 3];
                    const _Float16 hi = (_Float16)x;
                    hv = (_Float16)(x - (float)hi);
                } else if (k < 126) {
                    const int km = k - 84;
                    hv = (_Float16)(jr[km] - jr[km % 3]);
                } else {
                    hv = (_Float16)1.0f;
                }
                s[j] = hv;
            }
            *((half8*)&Alds[r][gi * 8]) = s;
        }
    }
    __syncthreads();

    // ---- x fragments (B-operand of swapped mfma) from LDS ----
    half8 a[2][4];
#pragma unroll
    for (int mt = 0; mt < 2; ++mt)
#pragma unroll
        for (int ks = 0; ks < 4; ++ks)
            a[mt][ks] = *((const half8*)&Alds[mt * 16 + lm][ks * 32 + g * 8]);

    // angle partials: [mt][d-pair] as f32x2
    f32x2 angp[2][4];
#pragma unroll
    for (int mt = 0; mt < 2; ++mt)
#pragma unroll
        for (int p = 0; p < 4; ++p) angp[mt][p] = (f32x2){0.f, 0.f};

    const half8* Bf = (const half8*)B1f;
#pragma unroll 4
    for (int nt = 0; nt < 16; ++nt) {
        const int ntile = w * 16 + nt;
        half8 bc[4];
#pragma unroll
        for (int ks = 0; ks < 4; ++ks)
            bc[ks] = Bf[(ks * 64 + ntile) * 64 + lane];

        f32x4 acc0 = (f32x4){0.f, 0.f, 0.f, 0.f};
        f32x4 acc1 = (f32x4){0.f, 0.f, 0.f, 0.f};
#pragma unroll
        for (int ks = 0; ks < 4; ++ks) {
            acc0 = __builtin_amdgcn_mfma_f32_16x16x32_f16(bc[ks], a[0][ks], acc0, 0, 0, 0);
            acc1 = __builtin_amdgcn_mfma_f32_16x16x32_f16(bc[ks], a[1][ks], acc1, 0, 0, 0);
        }

        // epilogue: lane holds h[n][m], n = ntile*16 + g*4 + r, m = mt*16+lm
#pragma unroll
        for (int r = 0; r < 4; ++r) {
            const long n = (long)ntile * 16 + g * 4 + r;
            const f32x4 wa = *((const f32x4*)(W2p + n * 8));
            const f32x4 wb = *((const f32x4*)(W2p + n * 8 + 4));
            const f32x2 w01 = (f32x2){wa[0], wa[1]};
            const f32x2 w23 = (f32x2){wa[2], wa[3]};
            const f32x2 w45 = (f32x2){wb[0], wb[1]};
            const f32x2 w67 = (f32x2){wb[2], wb[3]};
            const float h0 = fmaxf(acc0[r], 0.f);
            const float h1 = fmaxf(acc1[r], 0.f);
            const f32x2 h0v = (f32x2){h0, h0};
            const f32x2 h1v = (f32x2){h1, h1};
            angp[0][0] = __builtin_elementwise_fma(h0v, w01, angp[0][0]);
            angp[0][1] = __builtin_elementwise_fma(h0v, w23, angp[0][1]);
            angp[0][2] = __builtin_elementwise_fma(h0v, w45, angp[0][2]);
            angp[0][3] = __builtin_elementwise_fma(h0v, w67, angp[0][3]);
            angp[1][0] = __builtin_elementwise_fma(h1v, w01, angp[1][0]);
            angp[1][1] = __builtin_elementwise_fma(h1v, w23, angp[1][1]);
            angp[1][2] = __builtin_elementwise_fma(h1v, w45, angp[1][2]);
            angp[1][3] = __builtin_elementwise_fma(h1v, w67, angp[1][3]);
        }
    }

    // reduce across the 4 lane-groups (same m=lm, different n-slices)
    float red[2][8];
#pragma unroll
    for (int mt = 0; mt < 2; ++mt)
#pragma unroll
        for (int p = 0; p < 4; ++p) {
            red[mt][p * 2 + 0] = angp[mt][p][0];
            red[mt][p * 2 + 1] = angp[mt][p][1];
        }
#pragma unroll
    for (int mt = 0; mt < 2; ++mt)
#pragma unroll
        for (int i = 0; i < 8; ++i) {
            float v = red[mt][i];
            v += __shfl_xor(v, 16, 64);
            v += __shfl_xor(v, 32, 64);
            red[mt][i] = v;
        }
    if (lane < 16) {
#pragma unroll
        for (int mt = 0; mt < 2; ++mt)
#pragma unroll
            for (int i = 0; i < 8; ++i)
                atomicAdd(&sbuf[mt * 16 + lane][i], red[mt][i]);
    }
    __syncthreads();

    // ---- write angles ----
    {
        const int m = tid >> 3, d = tid & 7;
        if (d < 7)
            out[(bm + m) * 7 + d] = sbuf[m][d] + b2[d];
    }

    // ---- FK + Kabsch for this tile's 32 rows (threads 0..31) ----
    if (tid < 32) {
        const long b = bm + tid;
        const float* jr = joints + b * DIM;
        const float j0x = jr[0], j0y = jr[1], j0z = jr[2];

        float ang[NDOF];
#pragma unroll
        for (int d = 0; d < NDOF; ++d) ang[d] = sbuf[tid][d] + b2[d];

        float R00=1.f,R01=0.f,R02=0.f, R10=0.f,R11=1.f,R12=0.f, R20=0.f,R21=0.f,R22=1.f;
        float px=0.f, py=0.f, pz=0.f;
        float Hr00=0.f,Hr01=0.f,Hr02=0.f,Hr10=0.f,Hr11=0.f,Hr12=0.f,Hr20=0.f,Hr21=0.f,Hr22=0.f;
        float sPx=0.f, sPy=0.f, sPz=0.f;
        float sQx=0.f, sQy=0.f, sQz=0.f;
        const float LL[NDOF] = {0.333f,0.316f,0.384f,0.088f,0.107f,0.103f,0.1f};

#pragma unroll
        for (int j = 0; j < NDOF; ++j) {
            float s, c;
            sincosf(ang[j], &s, &c);
            if ((j & 1) == 0) {
                float a0=R00, a1=R01; R00 = c*a0 + s*a1; R01 = c*a1 - s*a0;
                float b0=R10, b1v=R11; R10 = c*b0 + s*b1v; R11 = c*b1v - s*b0;
                float c0=R20, c1=R21; R20 = c*c0 + s*c1; R21 = c*c1 - s*c0;
            } else {
                float a0=R00, a2=R02; R00 = c*a0 - s*a2; R02 = s*a0 + c*a2;
                float b0=R10, b2v=R12; R10 = c*b0 - s*b2v; R12 = s*b0 + c*b2v;
                float c0=R20, c2=R22; R20 = c*c0 - s*c2; R22 = s*c0 + c*c2;
            }
            px = fmaf(LL[j], R02, px);
            py = fmaf(LL[j], R12, py);
            pz = fmaf(LL[j], R22, pz);
            {
                const float qx = jr[6*j+0] - j0x, qy = jr[6*j+1] - j0y, qz = jr[6*j+2] - j0z;
                sQx += qx; sQy += qy; sQz += qz;
                sPx += px; sPy += py; sPz += pz;
                Hr00 = fmaf(px, qx, Hr00); Hr01 = fmaf(px, qy, Hr01); Hr02 = fmaf(px, qz, Hr02);
                Hr10 = fmaf(py, qx, Hr10); Hr11 = fmaf(py, qy, Hr11); Hr12 = fmaf(py, qz, Hr12);
                Hr20 = fmaf(pz, qx, Hr20); Hr21 = fmaf(pz, qy, Hr21); Hr22 = fmaf(pz, qz, Hr22);
            }
            {
                const float ox = fmaf(0.05f, R00, px);
                const float oy = fmaf(0.05f, R10, py);
                const float oz = fmaf(0.05f, R20, pz);
                const float qx = jr[6*j+3] - j0x, qy = jr[6*j+4] - j0y, qz = jr[6*j+5] - j0z;
                sQx += qx; sQy += qy; sQz += qz;
                sPx += ox; sPy += oy; sPz += oz;
                Hr00 = fmaf(ox, qx, Hr00); Hr01 = fmaf(ox, qy, Hr01); Hr02 = fmaf(ox, qz, Hr02);
                Hr10 = fmaf(oy, qx, Hr10); Hr11 = fmaf(oy, qy, Hr11); Hr12 = fmaf(oy, qz, Hr12);
                Hr20 = fmaf(oz, qx, Hr20); Hr21 = fmaf(oz, qy, Hr21); Hr22 = fmaf(oz, qz, Hr22);
            }
        }

        const double inv14 = 1.0 / 14.0;
        const double cpx = (double)sPx * inv14, cpy = (double)sPy * inv14, cpz = (double)sPz * inv14;
        const double cqx = (double)sQx * inv14, cqy = (double)sQy * inv14, cqz = (double)sQz * inv14;

        const double h00 = (double)Hr00 - 14.0*cpx*cqx, h01 = (double)Hr01 - 14.0*cpx*cqy, h02 = (double)Hr02 - 14.0*cpx*cqz;
        const double h10 = (double)Hr10 - 14.0*cpy*cqx, h11 = (double)Hr11 - 14.0*cpy*cqy, h12 = (double)Hr12 - 14.0*cpy*cqz;
        const double h20 = (double)Hr20 - 14.0*cpz*cqx, h21 = (double)Hr21 - 14.0*cpz*cqy, h22 = (double)Hr22 - 14.0*cpz*cqz;

        double m00 = h00*h00 + h10*h10 + h20*h20;
        double m01 = h00*h01 + h10*h11 + h20*h21;
        double m02 = h00*h02 + h10*h12 + h20*h22;
        double m11 = h01*h01 + h11*h11 + h21*h21;
        double m12 = h01*h02 + h11*h12 + h21*h22;
        double m22 = h02*h02 + h12*h12 + h22*h22;

        double v00=1.0, v01=0.0, v02=0.0;
        double v10=0.0, v11=1.0, v12=0.0;
        double v20=0.0, v21=0.0, v22=1.0;

#pragma unroll
        for (int sw = 0; sw < 5; ++sw) {
            JROT(m00, m11, m01, m02, m12, v00, v01, v10, v11, v20, v21);
            JROT(m00, m22, m02, m01, m12, v00, v02, v10, v12, v20, v22);
            JROT(m11, m22, m12, m01, m02, v01, v02, v11, v12, v21, v22);
        }

        double e0 = m00, e1 = m11, e2 = m22;
        if (e0 < e1) SWAP_EIG(e0, e1, v00, v01, v10, v11, v20, v21);
        if (e0 < e2) SWAP_EIG(e0, e2, v00, v02, v10, v12, v20, v22);
        if (e1 < e2) SWAP_EIG(e1, e2, v01, v02, v11, v12, v21, v22);

        const double s0 = sqrt(fmax(e0, 0.0));
        const double s1 = sqrt(fmax(e1, 0.0));
        const double s2 = sqrt(fmax(e2, 0.0));

        const double det = h00*(h11*h22 - h12*h21) - h01*(h10*h22 - h12*h20) + h02*(h10*h21 - h11*h20);
        const double dsg = (det >= 0.0) ? 1.0 : -1.0;

        const double tiny = 1e-30;
        const double g0 = 1.0 / fmax(s0, tiny);
        const double g1 = 1.0 / fmax(s1, tiny);
        const double g2 = dsg / fmax(s2, tiny);

        const double K00 = g0*v00*v00 + g1*v01*v01 + g2*v02*v02;
        const double K01 = g0*v00*v10 + g1*v01*v11 + g2*v02*v12;
        const double K02 = g0*v00*v20 + g1*v01*v21 + g2*v02*v22;
        const double K11 = g0*v10*v10 + g1*v11*v11 + g2*v12*v12;
        const double K12 = g0*v10*v20 + g1*v11*v21 + g2*v12*v22;
        const double K22 = g0*v20*v20 + g1*v21*v21 + g2*v22*v22;

        const double r00 = K00*h00 + K01*h01 + K02*h02;
        const double r01 = K00*h10 + K01*h11 + K02*h12;
        const double r02 = K00*h20 + K01*h21 + K02*h22;
        const double r10 = K01*h00 + K11*h01 + K12*h02;
        const double r11 = K01*h10 + K11*h11 + K12*h12;
        const double r12 = K01*h20 + K11*h21 + K12*h22;
        const double r20 = K02*h00 + K12*h01 + K22*h02;
        const double r21 = K02*h10 + K12*h11 + K22*h12;
        const double r22 = K02*h20 + K12*h21 + K22*h22;

        const double tx = cqx - (r00*cpx + r01*cpy + r02*cpz) + (double)j0x;
        const double ty = cqy - (r10*cpx + r11*cpy + r12*cpz) + (double)j0y;
        const double tz = cqz - (r20*cpx + r21*cpy + r22*cpz) + (double)j0z;

        float* po = out + (long)B_ * NDOF + b * 16;
        po[0]  = (float)r00; po[1]  = (float)r01; po[2]  = (float)r02; po[3]  = (float)tx;
        po[4]  = (float)r10; po[5]  = (float)r11; po[6]  = (float)r12; po[7]  = (float)ty;
        po[8]  = (float)r20; po[9]  = (float)r21; po[10] = (float)r22; po[11] = (float)tz;
        po[12] = 0.f; po[13] = 0.f; po[14] = 0.f; po[15] = 1.f;
    }
}

extern "C" void kernel_launch(void* const* d_in, const int* in_sizes, int n_in,
                              void* d_out, int out_size, void* d_ws, size_t ws_size,
                              hipStream_t stream) {
    const float* joints = (const float*)d_in[0];
    const float* W1     = (const float*)d_in[1];
    const float* b1     = (const float*)d_in[2];
    const float* W2     = (const float*)d_in[3];
    const float* b2     = (const float*)d_in[4];
    float* out = (float*)d_out;

    _Float16* B1f = (_Float16*)d_ws;                          // 256 KB
    float*    W2p = (float*)((char*)d_ws + 262144);           // 32 KB

    hipLaunchKernelGGL(prep_kernel, dim3(68), dim3(256), 0, stream,
                       W1, b1, W2, B1f, W2p);

    hipLaunchKernelGGL(mlp_fk_kernel, dim3(B_ / 32), dim3(256), 0, stream,
                       joints, B1f, W2p, b2, out);
}